// Round 2
// baseline (1568.536 us; speedup 1.0000x reference)
//
#include <hip/hip_runtime.h>
#include <hip/hip_bf16.h>

// Sparse BasicBlock: conv1 -> BN1 -> ReLU -> conv2 -> BN2 -> +x -> ReLU
// Streaming (atomic-free) formulation:
//   rank/scan/perm: counting-sort permutation of the 3.5M pairs by out_idx (shared by both convs)
//   phaseA (per k): gather bf16 rows -> MFMA -> write message row to sorted slot (write-once)
//   phaseB: contiguous segment-sum of messages -> output rows + fused BN stats
// Fallback to the round-1 atomic-scatter path if ws_size is too small.

#define NNODES 262144
#define NC 64
#define NK 27
#define NP 131072
#define NPAIR (NK * NP)
#define EPSV 1e-5f
#define TILE 64
#define TPB 4

typedef float f32x4 __attribute__((ext_vector_type(4)));
typedef __bf16 bf16x8 __attribute__((ext_vector_type(8)));

// ---------------------------------------------------------------- prep: W -> bf16 transposed Wt[k][co][ci]
__global__ void prep_w(const float* __restrict__ W, __bf16* __restrict__ Wt) {
    int i = blockIdx.x * 256 + threadIdx.x;
    if (i >= NK * NC * NC) return;
    int k  = i >> 12;
    int n  = (i >> 6) & 63;
    int ci = i & 63;
    Wt[i] = (__bf16)W[k * 4096 + ci * 64 + n];
}

// ---------------------------------------------------------------- prep: x -> bf16
__global__ __launch_bounds__(256) void prep_x(const float* __restrict__ X, __bf16* __restrict__ Xb) {
    size_t i = (size_t)(blockIdx.x * 256 + threadIdx.x) * 8;
    f32x4 a = *(const f32x4*)(X + i);
    f32x4 b = *(const f32x4*)(X + i + 4);
    bf16x8 o;
#pragma unroll
    for (int j = 0; j < 4; ++j) { o[j] = (__bf16)a[j]; o[4 + j] = (__bf16)b[j]; }
    *(bf16x8*)(Xb + i) = o;
}

// ---------------------------------------------------------------- counting sort: rank within output bin
__global__ void rank_kernel(const int* __restrict__ ok, int* __restrict__ hist, int* __restrict__ rank) {
    int i = blockIdx.x * 256 + threadIdx.x;
    rank[i] = atomicAdd(&hist[ok[i]], 1);
}

// exclusive scan of hist[262144] -> start[], 256 blocks x 1024 elems
__global__ __launch_bounds__(256) void scan1(const int* __restrict__ hist, int* __restrict__ start,
                                             int* __restrict__ bsum) {
    __shared__ int sh[256];
    const int b = blockIdx.x, t = threadIdx.x;
    int4 v = *(const int4*)(hist + b * 1024 + t * 4);
    int s0 = v.x, s1 = s0 + v.y, s2 = s1 + v.z, s3 = s2 + v.w;
    sh[t] = s3;
    __syncthreads();
    for (int off = 1; off < 256; off <<= 1) {
        int val = (t >= off) ? sh[t - off] : 0;
        __syncthreads();
        sh[t] += val;
        __syncthreads();
    }
    int excl = (t == 0) ? 0 : sh[t - 1];
    if (t == 255) bsum[b] = sh[255];
    int4 o;
    o.x = excl; o.y = excl + s0; o.z = excl + s1; o.w = excl + s2;
    *(int4*)(start + b * 1024 + t * 4) = o;
}

__global__ __launch_bounds__(256) void scan2(int* __restrict__ bsum) {
    __shared__ int sh[256];
    const int t = threadIdx.x;
    sh[t] = bsum[t];
    __syncthreads();
    for (int off = 1; off < 256; off <<= 1) {
        int val = (t >= off) ? sh[t - off] : 0;
        __syncthreads();
        sh[t] += val;
        __syncthreads();
    }
    bsum[t] = (t == 0) ? 0 : sh[t - 1];
}

__global__ __launch_bounds__(256) void scan3(int* __restrict__ start, const int* __restrict__ bsum) {
    const int b = blockIdx.x, t = threadIdx.x;
    int add = bsum[b];
    int4 v = *(int4*)(start + b * 1024 + t * 4);
    v.x += add; v.y += add; v.z += add; v.w += add;
    *(int4*)(start + b * 1024 + t * 4) = v;
    if (b == 0 && t == 0) start[NNODES] = NPAIR;
}

// perm[p] = start[ok[p]] + rank[p]   (in-place over rank)
__global__ void perm_kernel(const int* __restrict__ ok, const int* __restrict__ start,
                            int* __restrict__ rank) {
    int i = blockIdx.x * 256 + threadIdx.x;
    rank[i] = start[ok[i]] + rank[i];
}

// ---------------------------------------------------------------- phase A: gather -> MFMA -> write msg row to sorted slot
template <bool BN>
__global__ __launch_bounds__(256)
void phaseA(const __bf16* __restrict__ Xb, const __bf16* __restrict__ Wt,
            const int* __restrict__ in_idx, const int* __restrict__ perm,
            const float* __restrict__ st, __bf16* __restrict__ msg) {
    const int k    = blockIdx.y;
    const int tid  = threadIdx.x;
    const int wave = tid >> 6;
    const int lane = tid & 63;
    const int l15  = lane & 15;
    const int l4   = lane >> 4;

    __shared__ __align__(16) __bf16 As[64 * 64];
    __shared__ __align__(16) __bf16 Cs[64 * 64];
    __shared__ float s_s[64], s_t[64];

    if (BN && tid < 64) { s_s[tid] = st[tid]; s_t[tid] = st[64 + tid]; }

    bf16x8 bfrag[4][2];
    const __bf16* Wk = Wt + k * 4096;
#pragma unroll
    for (int nt = 0; nt < 4; ++nt)
#pragma unroll
        for (int ks = 0; ks < 2; ++ks)
            bfrag[nt][ks] = *(const bf16x8*)(Wk + (nt * 16 + l15) * 64 + ks * 32 + l4 * 8);

    const int* ik = in_idx + k * NP;
    const int* pm = perm + k * NP;
    const int r = tid >> 2;
    const int q = tid & 3;
    char* Ab = (char*)As;
    char* Cb = (char*)Cs;
    const int rb = wave * 16;

    __syncthreads();   // s_s visible before first gather

    int p0 = blockIdx.x * TPB * TILE;
    for (int t = 0; t < TPB; ++t, p0 += TILE) {
        const int gidx = ik[p0 + r];
        const int prow = pm[p0 + r];
        const __bf16* xr = Xb + (size_t)gidx * 64 + q * 16;
        bf16x8 c0 = *(const bf16x8*)xr;
        bf16x8 c1 = *(const bf16x8*)(xr + 8);
        if (BN) {
            const int cb = q * 16;
#pragma unroll
            for (int j = 0; j < 8; ++j) {
                float v0 = (float)c0[j], v1 = (float)c1[j];
                c0[j] = (__bf16)fmaxf(fmaf(v0, s_s[cb + j],     s_t[cb + j]),     0.0f);
                c1[j] = (__bf16)fmaxf(fmaf(v1, s_s[cb + 8 + j], s_t[cb + 8 + j]), 0.0f);
            }
        }
        *(bf16x8*)(Ab + r * 128 + (((2 * q)     ^ (r & 7)) << 4)) = c0;
        *(bf16x8*)(Ab + r * 128 + (((2 * q + 1) ^ (r & 7)) << 4)) = c1;
        __syncthreads();

        f32x4 acc[4];
#pragma unroll
        for (int nt = 0; nt < 4; ++nt)
#pragma unroll
            for (int j = 0; j < 4; ++j) acc[nt][j] = 0.0f;
#pragma unroll
        for (int ks = 0; ks < 2; ++ks) {
            const int row = rb + l15;
            bf16x8 a = *(const bf16x8*)(Ab + row * 128 + ((((ks << 2) + l4) ^ (row & 7)) << 4));
#pragma unroll
            for (int nt = 0; nt < 4; ++nt)
                acc[nt] = __builtin_amdgcn_mfma_f32_16x16x32_bf16(a, bfrag[nt][ks], acc[nt], 0, 0, 0);
        }

        // repack D fragments -> Cs (swizzled 16B chunks), bf16
#pragma unroll
        for (int rg = 0; rg < 4; ++rg) {
            const int row = rb + l4 * 4 + rg;
            char* cr = Cb + row * 128;
#pragma unroll
            for (int nt = 0; nt < 4; ++nt) {
                const int chunk = nt * 2 + (l15 >> 3);
                *(__bf16*)(cr + ((chunk ^ (row & 7)) << 4) + (l15 & 7) * 2) = (__bf16)acc[nt][rg];
            }
        }
        __syncthreads();

        // write message row (once, no atomics)
        bf16x8 o0 = *(bf16x8*)(Cb + r * 128 + (((2 * q)     ^ (r & 7)) << 4));
        bf16x8 o1 = *(bf16x8*)(Cb + r * 128 + (((2 * q + 1) ^ (r & 7)) << 4));
        __bf16* mr = msg + (size_t)prow * 64 + q * 16;
        *(bf16x8*)mr       = o0;
        *(bf16x8*)(mr + 8) = o1;
    }
}

// ---------------------------------------------------------------- phase B: segment sum + BN stats
template <bool FIRST>
__global__ __launch_bounds__(256)
void phaseB(const __bf16* __restrict__ msg, const int* __restrict__ start,
            __bf16* __restrict__ outb, float* __restrict__ outf, float* __restrict__ sums) {
    const int wave = threadIdx.x >> 6;
    const int lane = threadIdx.x & 63;
    float s = 0.0f, s2 = 0.0f;
    for (int n0 = blockIdx.x * 4; n0 < NNODES; n0 += gridDim.x * 4) {
        const int n = n0 + wave;
        const int b = start[n], e = start[n + 1];
        float acc = 0.0f;
        for (int i = b; i < e; ++i) acc += (float)msg[(size_t)i * 64 + lane];
        if (FIRST) outb[(size_t)n * 64 + lane] = (__bf16)acc;
        else       outf[(size_t)n * 64 + lane] = acc;
        s += acc;
        s2 += acc * acc;
    }
    __shared__ float red[8][64];
    red[wave][lane]     = s;
    red[4 + wave][lane] = s2;
    __syncthreads();
    if (wave == 0) {
        float ts  = red[0][lane] + red[1][lane] + red[2][lane] + red[3][lane];
        float ts2 = red[4][lane] + red[5][lane] + red[6][lane] + red[7][lane];
        unsafeAtomicAdd(&sums[lane], ts);
        unsafeAtomicAdd(&sums[64 + lane], ts2);
    }
}

// ---------------------------------------------------------------- BN params: st[c]=scale, st[64+c]=shift
__global__ void bn_params(const float* __restrict__ sums, const float* __restrict__ gamma,
                          const float* __restrict__ beta, float* __restrict__ st) {
    int c = threadIdx.x;
    const float inv = 1.0f / (float)NNODES;
    float mean = sums[c] * inv;
    float var  = sums[64 + c] * inv - mean * mean;
    float s    = gamma[c] * rsqrtf(var + EPSV);
    st[c]      = s;
    st[64 + c] = beta[c] - mean * s;
}

// ---------------------------------------------------------------- final: out = relu(h2*s + t + x), in place
__global__ __launch_bounds__(256)
void final_kernel(float* __restrict__ Out, const float* __restrict__ X, const float* __restrict__ st) {
    __shared__ float s_s[64], s_t[64];
    if (threadIdx.x < 64) { s_s[threadIdx.x] = st[threadIdx.x]; s_t[threadIdx.x] = st[64 + threadIdx.x]; }
    __syncthreads();
    int i = blockIdx.x * 256 + threadIdx.x;
    f32x4 h  = *(f32x4*)(Out + (size_t)i * 4);
    f32x4 xv = *(const f32x4*)(X + (size_t)i * 4);
    const int cb = (i & 15) * 4;
    f32x4 o;
#pragma unroll
    for (int j = 0; j < 4; ++j)
        o[j] = fmaxf(fmaf(h[j], s_s[cb + j], s_t[cb + j]) + xv[j], 0.0f);
    *(f32x4*)(Out + (size_t)i * 4) = o;
}

// ================================================================ fallback (round-1 atomic path)
template <bool BN>
__global__ __launch_bounds__(256)
void conv_kernel(const float* __restrict__ X, const __bf16* __restrict__ Wt,
                 const int* __restrict__ in_idx, const int* __restrict__ out_idx,
                 const float* __restrict__ st, float* __restrict__ Out) {
    const int k    = blockIdx.y;
    const int tid  = threadIdx.x;
    const int wave = tid >> 6;
    const int lane = tid & 63;
    const int l15  = lane & 15;
    const int l4   = lane >> 4;
    __shared__ __align__(16) __bf16 As[64 * 64];
    __shared__ int oks[TILE];
    __shared__ float s_s[64], s_t[64];
    if (BN && tid < 64) { s_s[tid] = st[tid]; s_t[tid] = st[64 + tid]; }
    bf16x8 bfrag[4][2];
    const __bf16* Wk = Wt + k * 4096;
#pragma unroll
    for (int nt = 0; nt < 4; ++nt)
#pragma unroll
        for (int ks = 0; ks < 2; ++ks)
            bfrag[nt][ks] = *(const bf16x8*)(Wk + (nt * 16 + l15) * 64 + ks * 32 + l4 * 8);
    const int* ik = in_idx + k * NP;
    const int* ok = out_idx + k * NP;
    const int r = tid >> 2;
    const int q = tid & 3;
    char* Abase = (char*)As;
    const int rb = wave * 16;
    __syncthreads();
    int p0 = (blockIdx.x * 8) * TILE;
    for (int t = 0; t < 8; ++t, p0 += TILE) {
        if (tid < TILE) oks[tid] = ok[p0 + tid];
        const float* xr = X + (size_t)ik[p0 + r] * 64 + q * 16;
        f32x4 v0 = *(const f32x4*)(xr + 0);
        f32x4 v1 = *(const f32x4*)(xr + 4);
        f32x4 v2 = *(const f32x4*)(xr + 8);
        f32x4 v3 = *(const f32x4*)(xr + 12);
        float vals[16];
        *(f32x4*)&vals[0]  = v0; *(f32x4*)&vals[4]  = v1;
        *(f32x4*)&vals[8]  = v2; *(f32x4*)&vals[12] = v3;
        if (BN) {
            const int cb = q * 16;
#pragma unroll
            for (int j = 0; j < 16; ++j)
                vals[j] = fmaxf(fmaf(vals[j], s_s[cb + j], s_t[cb + j]), 0.0f);
        }
        bf16x8 c0, c1;
#pragma unroll
        for (int j = 0; j < 8; ++j) { c0[j] = (__bf16)vals[j]; c1[j] = (__bf16)vals[8 + j]; }
        *(bf16x8*)(Abase + r * 128 + (((2 * q)     ^ (r & 7)) << 4)) = c0;
        *(bf16x8*)(Abase + r * 128 + (((2 * q + 1) ^ (r & 7)) << 4)) = c1;
        __syncthreads();
        f32x4 acc[4];
#pragma unroll
        for (int nt = 0; nt < 4; ++nt)
#pragma unroll
            for (int j = 0; j < 4; ++j) acc[nt][j] = 0.0f;
#pragma unroll
        for (int ks = 0; ks < 2; ++ks) {
            const int row = rb + l15;
            bf16x8 a = *(const bf16x8*)(Abase + row * 128 + ((((ks << 2) + l4) ^ (row & 7)) << 4));
#pragma unroll
            for (int nt = 0; nt < 4; ++nt)
                acc[nt] = __builtin_amdgcn_mfma_f32_16x16x32_bf16(a, bfrag[nt][ks], acc[nt], 0, 0, 0);
        }
#pragma unroll
        for (int rg = 0; rg < 4; ++rg) {
            const int rr = rb + l4 * 4 + rg;
            float* orow = Out + (size_t)oks[rr] * 64;
#pragma unroll
            for (int nt = 0; nt < 4; ++nt)
                unsafeAtomicAdd(orow + nt * 16 + l15, acc[nt][rg]);
        }
        __syncthreads();
    }
}

__global__ __launch_bounds__(256)
void bn_stats(const float* __restrict__ H, float* __restrict__ sums) {
    const int c    = threadIdx.x & 63;
    const int slot = threadIdx.x >> 6;
    float s = 0.0f, s2 = 0.0f;
    for (int row = blockIdx.x * 4 + slot; row < NNODES; row += gridDim.x * 4) {
        float v = H[(size_t)row * 64 + c];
        s += v; s2 += v * v;
    }
    __shared__ float red[8][64];
    red[slot][c] = s; red[4 + slot][c] = s2;
    __syncthreads();
    if (slot == 0) {
        s  = red[0][c] + red[1][c] + red[2][c] + red[3][c];
        s2 = red[4][c] + red[5][c] + red[6][c] + red[7][c];
        unsafeAtomicAdd(&sums[c], s);
        unsafeAtomicAdd(&sums[64 + c], s2);
    }
}

// ---------------------------------------------------------------- launch
extern "C" void kernel_launch(void* const* d_in, const int* in_sizes, int n_in,
                              void* d_out, int out_size, void* d_ws, size_t ws_size,
                              hipStream_t stream) {
    const float* x      = (const float*)d_in[0];
    const float* W1     = (const float*)d_in[1];
    // b1 (d_in[2]) cancels through BN1 mean-subtraction — skipped.
    const float* gamma1 = (const float*)d_in[3];
    const float* beta1  = (const float*)d_in[4];
    const float* W2     = (const float*)d_in[5];
    // b2 (d_in[6]) cancels through BN2 — skipped.
    const float* gamma2 = (const float*)d_in[7];
    const float* beta2  = (const float*)d_in[8];
    const int* in_idx   = (const int*)d_in[9];
    const int* out_idx  = (const int*)d_in[10];
    float* out = (float*)d_out;

    char* ws = (char*)d_ws;
    size_t off = 0;
    auto alloc = [&](size_t bytes) -> char* {
        char* p = ws + off;
        off = (off + bytes + 255) & ~(size_t)255;
        return p;
    };

    __bf16* msg   = (__bf16*)alloc((size_t)NPAIR * 64 * 2);     // 453 MB
    __bf16* xbf   = (__bf16*)alloc((size_t)NNODES * 64 * 2);    // 33.5 MB
    __bf16* h1bf  = (__bf16*)alloc((size_t)NNODES * 64 * 2);    // 33.5 MB
    int*    perm  = (int*)alloc((size_t)NPAIR * 4);             // 14.2 MB
    int*    hist  = (int*)alloc((size_t)NNODES * 4);            // 1 MB
    int*    startv= (int*)alloc((size_t)(NNODES + 64) * 4);     // 1 MB
    int*    bsum  = (int*)alloc(1024);
    __bf16* Wt1   = (__bf16*)alloc(NK * 4096 * 2);
    __bf16* Wt2   = (__bf16*)alloc(NK * 4096 * 2);
    float*  sums1 = (float*)alloc(512);
    float*  st1   = (float*)alloc(512);
    float*  sums2 = (float*)alloc(512);
    float*  st2   = (float*)alloc(512);

    if (off <= ws_size) {
        // ---------------- streaming path
        hipMemsetAsync(hist, 0, (size_t)NNODES * 4, stream);
        hipMemsetAsync(sums1, 0, 512, stream);
        hipMemsetAsync(sums2, 0, 512, stream);

        prep_x<<<NNODES * 64 / 8 / 256, 256, 0, stream>>>(x, xbf);
        prep_w<<<(NK * NC * NC + 255) / 256, 256, 0, stream>>>(W1, Wt1);
        prep_w<<<(NK * NC * NC + 255) / 256, 256, 0, stream>>>(W2, Wt2);

        rank_kernel<<<NPAIR / 256, 256, 0, stream>>>(out_idx, hist, perm);
        scan1<<<256, 256, 0, stream>>>(hist, startv, bsum);
        scan2<<<1, 256, 0, stream>>>(bsum);
        scan3<<<256, 256, 0, stream>>>(startv, bsum);
        perm_kernel<<<NPAIR / 256, 256, 0, stream>>>(out_idx, startv, perm);

        dim3 agrid(NP / TILE / TPB, NK);   // (512, 27)
        phaseA<false><<<agrid, 256, 0, stream>>>(xbf, Wt1, in_idx, perm, nullptr, msg);
        phaseB<true><<<2048, 256, 0, stream>>>(msg, startv, h1bf, nullptr, sums1);
        bn_params<<<1, 64, 0, stream>>>(sums1, gamma1, beta1, st1);
        phaseA<true><<<agrid, 256, 0, stream>>>(h1bf, Wt2, in_idx, perm, st1, msg);
        phaseB<false><<<2048, 256, 0, stream>>>(msg, startv, nullptr, out, sums2);
        bn_params<<<1, 64, 0, stream>>>(sums2, gamma2, beta2, st2);
        final_kernel<<<NNODES * 64 / 4 / 256, 256, 0, stream>>>(out, x, st2);
    } else {
        // ---------------- fallback: round-1 atomic path (ws too small)
        size_t o2 = 0;
        auto alloc2 = [&](size_t bytes) -> char* {
            char* p = ws + o2;
            o2 = (o2 + bytes + 255) & ~(size_t)255;
            return p;
        };
        float*  h1    = (float*)alloc2((size_t)NNODES * 64 * 4);
        float*  fsums1= (float*)alloc2(512);
        float*  fst1  = (float*)alloc2(512);
        float*  fsums2= (float*)alloc2(512);
        float*  fst2  = (float*)alloc2(512);
        __bf16* fWt1  = (__bf16*)alloc2(NK * 4096 * 2);
        __bf16* fWt2  = (__bf16*)alloc2(NK * 4096 * 2);

        hipMemsetAsync(h1, 0, (size_t)NNODES * 64 * 4, stream);
        hipMemsetAsync(fsums1, 0, 512, stream);
        hipMemsetAsync(fsums2, 0, 512, stream);
        hipMemsetAsync(d_out, 0, (size_t)out_size * 4, stream);

        prep_w<<<(NK * NC * NC + 255) / 256, 256, 0, stream>>>(W1, fWt1);
        prep_w<<<(NK * NC * NC + 255) / 256, 256, 0, stream>>>(W2, fWt2);
        dim3 cgrid(NP / TILE / 8, NK);
        conv_kernel<false><<<cgrid, 256, 0, stream>>>(x, fWt1, in_idx, out_idx, nullptr, h1);
        bn_stats<<<1024, 256, 0, stream>>>(h1, fsums1);
        bn_params<<<1, 64, 0, stream>>>(fsums1, gamma1, beta1, fst1);
        conv_kernel<true><<<cgrid, 256, 0, stream>>>(h1, fWt2, in_idx, out_idx, fst1, out);
        bn_stats<<<1024, 256, 0, stream>>>(out, fsums2);
        bn_params<<<1, 64, 0, stream>>>(fsums2, gamma2, beta2, fst2);
        final_kernel<<<NNODES * 64 / 4 / 256, 256, 0, stream>>>(out, x, st2 ? fst2 : fst2);
    }
}